// Round 7
// baseline (127.623 us; speedup 1.0000x reference)
//
#include <hip/hip_runtime.h>
#include <stdint.h>
#include <limits.h>

// Flip to 0 if validation shows wrong RNG path (legacy non-partitionable threefry).
#define THREEFRY_PARTITIONABLE 1

#define NTK   512      // threads per block (both kernels): 8 waves
#define NWAVE (NTK/64)
#define NBUCK 4096     // histogram buckets (monotone float key >> 20)
#define BPT   (NBUCK/NTK)   // buckets per thread in the block scan (8)
#define CAPS  256      // per-split candidate cap (workspace)
#define CAPG  2048     // per-row gathered candidate cap (LDS, finalize)
#define CAPF  512      // per-row filtered candidate cap (LDS, finalize)
#define KMAX  512      // max supported top_k
#define SMAX  32
#define CHUNK_TARGET 32768   // ~elements per split block

// ---- fallback (round-1 proven) kernel constants ----
#define NT1   1024
#define CAP1  4096

#if __has_builtin(__builtin_amdgcn_exp2f)
#define FAST_EXP2(x) __builtin_amdgcn_exp2f(x)
#else
#define FAST_EXP2(x) exp2f(x)
#endif

__device__ __forceinline__ uint32_t rotl32(uint32_t v, int r) {
  return (v << r) | (v >> (32 - r));
}
__device__ __forceinline__ void tfround(uint32_t& x0, uint32_t& x1, int r) {
  x0 += x1; x1 = rotl32(x1, r); x1 ^= x0;
}
// JAX threefry2x32: 20 rounds, rotations [13,15,26,6]/[17,29,16,24]
__device__ __forceinline__ void threefry2x32(uint32_t k0, uint32_t k1,
                                             uint32_t x0, uint32_t x1,
                                             uint32_t& o0, uint32_t& o1) {
  uint32_t k2 = k0 ^ k1 ^ 0x1BD11BDAu;
  x0 += k0; x1 += k1;
  tfround(x0,x1,13); tfround(x0,x1,15); tfround(x0,x1,26); tfround(x0,x1,6);
  x0 += k1; x1 += k2 + 1u;
  tfround(x0,x1,17); tfround(x0,x1,29); tfround(x0,x1,16); tfround(x0,x1,24);
  x0 += k2; x1 += k0 + 2u;
  tfround(x0,x1,13); tfround(x0,x1,15); tfround(x0,x1,26); tfround(x0,x1,6);
  x0 += k0; x1 += k1 + 3u;
  tfround(x0,x1,17); tfround(x0,x1,29); tfround(x0,x1,16); tfround(x0,x1,24);
  x0 += k1; x1 += k2 + 4u;
  tfround(x0,x1,13); tfround(x0,x1,15); tfround(x0,x1,26); tfround(x0,x1,6);
  x0 += k2; x1 += k0 + 5u;
  o0 = x0; o1 = x1;
}
// Exponential noise for flat element i: jax.random.exponential(fold_in(key(0),1))
__device__ __forceinline__ float jax_noise(uint32_t kn0, uint32_t kn1,
                                           unsigned long long i,
                                           unsigned long long total) {
  uint32_t o0, o1, bits;
#if THREEFRY_PARTITIONABLE
  threefry2x32(kn0, kn1, (uint32_t)(i >> 32), (uint32_t)(i & 0xFFFFFFFFull), o0, o1);
  bits = o0 ^ o1;
#else
  unsigned long long H = total >> 1;
  if (i < H) { threefry2x32(kn0, kn1, (uint32_t)i, (uint32_t)(i + H), o0, o1); bits = o0; }
  else       { threefry2x32(kn0, kn1, (uint32_t)(i - H), (uint32_t)i, o0, o1); bits = o1; }
#endif
  float u = __uint_as_float((bits >> 9) | 0x3f800000u) - 1.0f;  // [0,1)
  float e = -log1pf(-u);
  return fmaxf(e, 1e-10f);
}
// Monotone float -> uint32 key (total order preserving)
__device__ __forceinline__ uint32_t fkey(float f) {
  uint32_t u = __float_as_uint(f);
  return u ^ ((u >> 31) ? 0xFFFFFFFFu : 0x80000000u);
}
// Smallest float whose key >= keyT (bucket floor). keyT==0 -> -inf (emit all).
__device__ __forceinline__ float unfkey_floor(uint32_t keyT) {
  if (keyT == 0u) return -INFINITY;
  return __uint_as_float((keyT & 0x80000000u) ? (keyT ^ 0x80000000u) : ~keyT);
}
__device__ __forceinline__ int clamp_k(int k) {
  if (k < 1) k = 1;
  if (k > KMAX) k = KMAX;
  return k;
}

// Block-parallel suffix-scan of hist -> bucket of the rank-k largest entry.
// beta_sh must be pre-zeroed; hist filled and barrier'd before the call.
// Conservative when hist holds a subset (undercount -> lower bucket).
__device__ __forceinline__ void block_kth_bucket(uint32_t* hist, uint32_t* wtot,
                                                 int* beta_sh, int k,
                                                 int tid, int lane, int wave) {
  const int base = tid * BPT;
  uint32_t tsum = 0;
#pragma unroll
  for (int j = 0; j < BPT; j++) tsum += hist[base + j];
  uint32_t incl = tsum;                    // inclusive suffix over lanes >= lane
  for (int off = 1; off < 64; off <<= 1) {
    uint32_t v = __shfl_down(incl, off);
    if (lane + off < 64) incl += v;
  }
  if (lane == 0) wtot[wave] = incl;
  __syncthreads();
  uint32_t above = incl - tsum;            // threads strictly above (same wave)
  for (int w = wave + 1; w < NWAVE; w++) above += wtot[w];
  if (above < (uint32_t)k && above + tsum >= (uint32_t)k) {
    uint32_t run = above;
    for (int j = BPT - 1; j >= 0; j--) {
      run += hist[base + j];
      if (run >= (uint32_t)k) { *beta_sh = base + j; break; }
    }
  }
  __syncthreads();
}

// ========= K1: single streaming pass: split max + UNSCALED exp2-sum + candidates
// dsum_sp = sum_i 2^(l_i*log2e/T) accumulated in f32 pairs, folded to f64
// (|l*log2e/T| <~ 32 << 127 so no overflow; finalize rescales by
// 2^(-m_g*log2e/T) in f64; D rel-err ~1e-6 << the 0.9-crossing margins).
// Selection on RAW logit bits (T>0, IEEE division monotone): thread-max
// histogram -> conservative keyT (subset undercount => bucket <= true kth
// bucket => emission superset of the split's top-k). Threads with
// tmax < floor(keyT) provably emit nothing and SKIP the re-scan pass.
__global__ __launch_bounds__(NTK)
void sampler_stream(const float* __restrict__ logits,
                    const float* __restrict__ temps,
                    const int* __restrict__ topk_ptr,
                    float* __restrict__ msArr,
                    double* __restrict__ dsumArr,
                    int* __restrict__ cntArr,
                    float2* __restrict__ pairs,
                    int B, int V, int S, int chunk) {
  const int blk = blockIdx.x;
  const int b = blk / S, sp = blk % S;
  const int tid = threadIdx.x, lane = tid & 63, wave = tid >> 6;

  __shared__ uint32_t hist[NBUCK];
  __shared__ float wm[NWAVE];
  __shared__ double wsum[NWAVE];
  __shared__ uint32_t wtot[NWAVE];
  __shared__ int beta_sh, cnum_sh;

  if (tid == 0) { beta_sh = 0; cnum_sh = 0; }
  for (int i = tid; i < NBUCK; i += NTK) hist[i] = 0;

  const float T = temps[b];
  const float cf = (float)(1.4426950408889634 / (double)T);  // log2e / T
  const int k = clamp_k(*topk_ptr);

  const int start = sp * chunk;
  const int end = min(start + chunk, V);
  const float* row = logits + (size_t)b * (size_t)V;
  const int n = end - start;
  const int n4 = n >> 2;                 // start is 4-aligned (chunk % 4 == 0)
  const float4* row4 = (const float4*)(row + start);

  // ---- single streaming pass: raw max + unscaled exp2 sum ----
  float tmax = -INFINITY;
  float acc0 = 0.f, acc1 = 0.f;
  for (int i = tid; i < n4; i += NTK) {
    float4 f = row4[i];
    tmax = fmaxf(tmax, fmaxf(fmaxf(f.x, f.y), fmaxf(f.z, f.w)));
    acc0 += FAST_EXP2(f.x * cf) + FAST_EXP2(f.z * cf);
    acc1 += FAST_EXP2(f.y * cf) + FAST_EXP2(f.w * cf);
  }
  for (int v = start + n4 * 4 + tid; v < end; v += NTK) {
    float f = row[v];
    tmax = fmaxf(tmax, f);
    acc0 += FAST_EXP2(f * cf);
  }

  // wave reductions
  float bm = tmax;
  for (int off = 32; off; off >>= 1)
    bm = fmaxf(bm, __shfl_down(bm, off));
  if (lane == 0) wm[wave] = bm;

  double ds = (double)acc0 + (double)acc1;
  for (int off = 32; off; off >>= 1)
    ds += __shfl_down(ds, off);
  if (lane == 0) wsum[wave] = ds;

  if (tmax != -INFINITY) atomicAdd(&hist[fkey(tmax) >> 20], 1u);
  __syncthreads();                        // hist zero + wm + wsum + hist atomics

  if (tid == 0) {
    float m_sp = wm[0];
#pragma unroll
    for (int w = 1; w < NWAVE; w++) m_sp = fmaxf(m_sp, wm[w]);
    msArr[blk] = m_sp;
    double t = 0.0;
    for (int w = 0; w < NWAVE; w++) t += wsum[w];
    dsumArr[blk] = t;                     // RAW (unscaled) exp2 sum
  }

  block_kth_bucket(hist, wtot, &beta_sh, k, tid, lane, wave);

  const float fT = unfkey_floor((uint32_t)beta_sh << 20);
  float2* myp = pairs + (size_t)blk * CAPS;

  // ---- emit pass: only threads whose OWN max clears the threshold re-scan
  // (tmax < fT => every element of this thread < fT => nothing to emit).
  if (tmax >= fT) {
    for (int i = tid; i < n4; i += NTK) {
      float4 f = row4[i];                 // L2-warm re-read, few threads active
      const int vb = start + i * 4;
      if (f.x >= fT) { int p = atomicAdd(&cnum_sh, 1); if (p < CAPS) myp[p] = make_float2(f.x, __int_as_float(vb)); }
      if (f.y >= fT) { int p = atomicAdd(&cnum_sh, 1); if (p < CAPS) myp[p] = make_float2(f.y, __int_as_float(vb + 1)); }
      if (f.z >= fT) { int p = atomicAdd(&cnum_sh, 1); if (p < CAPS) myp[p] = make_float2(f.z, __int_as_float(vb + 2)); }
      if (f.w >= fT) { int p = atomicAdd(&cnum_sh, 1); if (p < CAPS) myp[p] = make_float2(f.w, __int_as_float(vb + 3)); }
    }
    for (int v = start + n4 * 4 + tid; v < end; v += NTK) {
      float f = row[v];
      if (f >= fT) { int p = atomicAdd(&cnum_sh, 1); if (p < CAPS) myp[p] = make_float2(f, __int_as_float(v)); }
    }
  }
  __syncthreads();
  if (tid == 0) cntArr[blk] = min(cnum_sh, CAPS);
}

// ==================== K2: per-row finalize ====================
__global__ __launch_bounds__(NTK)
void sampler_finalize(const float* __restrict__ temps,
                      const int* __restrict__ topk_ptr,
                      const float* __restrict__ msArr,
                      const double* __restrict__ dsumArr,
                      const int* __restrict__ cntArr,
                      const float2* __restrict__ pairs,
                      int* __restrict__ out,
                      int B, int V, int S) {
  const int b = blockIdx.x;
  const int tid = threadIdx.x, lane = tid & 63, wave = tid >> 6;

  __shared__ uint32_t hist[NBUCK];
  __shared__ float gv[CAPG];
  __shared__ int   gi[CAPG];
  __shared__ float c2v[CAPF];
  __shared__ int   c2i[CAPF];
  __shared__ float c2p[CAPF];
  __shared__ float sv[KMAX];
  __shared__ int   si[KMAX];
  __shared__ float sc[KMAX];
  __shared__ int   offL[SMAX + 1];
  __shared__ int   cnL[SMAX];
  __shared__ float msL[SMAX];
  __shared__ double dsL[SMAX];
  __shared__ uint32_t wtot[NWAVE];
  __shared__ int beta_sh, cnt2_sh, L_sh;
  __shared__ float m_sh, D_sh;

  const int k = clamp_k(*topk_ptr);
  const float T = temps[b];

  if (tid == 0) { beta_sh = 0; cnt2_sh = 0; }
  if (tid < S) {                          // parallel preload of ALL split scalars
    msL[tid] = msArr[b * S + tid];
    dsL[tid] = dsumArr[b * S + tid];
    int c = cntArr[b * S + tid];
    cnL[tid] = (c < CAPS) ? c : CAPS;
  }
  for (int i = tid; i < NBUCK; i += NTK) hist[i] = 0;
  __syncthreads();

  if (tid == 0) {                         // prefix offsets from LDS (fast)
    int acc = 0;
    for (int j = 0; j < S; j++) { offL[j] = acc; acc += cnL[j]; }
    offL[S] = acc;
  }

  // D = float( (sum_sp raw_sp) * 2^(-m_g*log2e/T) ), f64 rescale once per row
  if (wave == 1 || (NWAVE == 1 && wave == 0)) {
    float msp = (lane < S) ? msL[lane] : -INFINITY;
    float mg = msp;
    for (int off = 32; off; off >>= 1)
      mg = fmaxf(mg, __shfl_down(mg, off));
    mg = __shfl(mg, 0);
    double term = (lane < S) ? dsL[lane] : 0.0;
    for (int off = 32; off; off >>= 1)
      term += __shfl_down(term, off);
    if (lane == 0) {
      const double cd = 1.4426950408889634 / (double)T;
      D_sh = (float)(term * exp2(-(double)mg * cd));
      m_sh = mg / T;     // == max over fl(l/T) (monotone IEEE division)
    }
  }
  __syncthreads();

  const int TC = min(offL[S], CAPG);

  // flat parallel gather of all candidates into LDS + exact-count histogram
  for (int t = tid; t < TC; t += NTK) {
    int j = 0;
#pragma unroll
    for (int jj = 1; jj <= SMAX; jj++)
      if (jj <= S) j += (t >= offL[jj]);
    float2 pr = pairs[(size_t)(b * S + j) * CAPS + (t - offL[j])];
    gv[t] = pr.x;
    gi[t] = __float_as_int(pr.y);
    atomicAdd(&hist[fkey(pr.x) >> 20], 1u);
  }
  __syncthreads();

  block_kth_bucket(hist, wtot, &beta_sh, k, tid, lane, wave);

  // filter down to elements >= global kth bucket floor (exact counts ->
  // bucket <= true kth element's bucket -> keep set superset of row top-k)
  const float fT = unfkey_floor((uint32_t)beta_sh << 20);
  for (int t = tid; t < TC; t += NTK) {
    float val = gv[t];
    if (val >= fT) {
      int pos = atomicAdd(&cnt2_sh, 1);
      if (pos < CAPF) { c2v[pos] = val; c2i[pos] = gi[t]; }
    }
  }
  __syncthreads();

  const int C = min(cnt2_sh, CAPF);
  const float m = m_sh, D = D_sh;
  // exact-path p for the ~150 survivors: real IEEE div + libm expf
  for (int i = tid; i < C; i += NTK)
    c2p[i] = expf(c2v[i] / T - m) / D;
  __syncthreads();

  // exact ranking: (p desc, idx asc) — JAX top_k / stable argsort tie rule
  for (int i = tid; i < C; i += NTK) {
    float pi = c2p[i];
    int   ii = c2i[i];
    int r = 0;
    for (int j = 0; j < C; j++) {
      float pj = c2p[j];
      r += (pj > pi) || (pj == pi && c2i[j] < ii);
    }
    if (r < k) { sv[r] = pi; si[r] = ii; }
  }
  __syncthreads();

  // top-p: sequential fp32 cumsum, keep prefix (first always kept)
  const int kk = (k < C) ? k : C;
  if (tid == 0) {
    float cum = 0.f;
    int L = 1;
    for (int j = 0; j < kk; j++) {
      cum += sv[j];
      if (j == 0) continue;
      if (cum <= 0.9f) L = j + 1; else break;
    }
    L_sh = L;
  }
  __syncthreads();

  const int L = L_sh;
  {
    uint32_t kn0, kn1;
    threefry2x32(0u, 0u, 0u, 1u, kn0, kn1);   // fold_in(key(0), 1)
    unsigned long long total = (unsigned long long)B * (unsigned long long)V;
    for (int j = tid; j < L; j += NTK) {
      unsigned long long flat = (unsigned long long)b * (unsigned long long)V
                              + (unsigned long long)si[j];
      sc[j] = sv[j] / jax_noise(kn0, kn1, flat, total);
    }
  }
  __syncthreads();

  if (tid == 0) {
    float bs = -1.0f;
    int   bi = INT_MAX;
    for (int j = 0; j < L; j++) {
      if (sc[j] > bs || (sc[j] == bs && si[j] < bi)) { bs = sc[j]; bi = si[j]; }
    }
    out[b] = bi;
  }
}

// ==================== Fallback: round-1 proven single kernel ==================
__global__ __launch_bounds__(NT1, 1)
void sampler_fallback(const float* __restrict__ logits,
                      const float* __restrict__ temps,
                      const int* __restrict__ topk_ptr,
                      int* __restrict__ out,
                      int B, int V) {
  const int b    = blockIdx.x;
  const int tid  = threadIdx.x;
  const int lane = tid & 63;
  const int wave = tid >> 6;

  __shared__ uint32_t hist[NBUCK];
  __shared__ float    cand_p[CAP1];
  __shared__ int      cand_i[CAP1];
  __shared__ float    wmax[16];
  __shared__ double   wsum[16];
  __shared__ float    svals[KMAX];
  __shared__ int      sidx[KMAX];
  __shared__ float    m_sh, D_sh;
  __shared__ int      beta_sh, cnum_sh, L_sh;

  const float T = temps[b];
  const float* row = logits + (size_t)b * (size_t)V;
  int k = clamp_k(*topk_ptr);
  if (k > V) k = V;

  if (tid == 0) { beta_sh = 1; cnum_sh = 0; }
  for (int i = tid; i < NBUCK; i += NT1) hist[i] = 0;
  __syncthreads();

  float t8[8];
#pragma unroll
  for (int j = 0; j < 8; j++) t8[j] = -INFINITY;
  float mymax = -INFINITY;
  for (int v = tid; v < V; v += NT1) {
    float s = row[v] / T;
    mymax = fmaxf(mymax, s);
    if (s > t8[0]) {
      t8[0] = s;
#pragma unroll
      for (int j = 1; j < 8; j++)
        if (t8[j-1] > t8[j]) { float tmp = t8[j]; t8[j] = t8[j-1]; t8[j-1] = tmp; }
    }
  }
  for (int off = 32; off > 0; off >>= 1)
    mymax = fmaxf(mymax, __shfl_down(mymax, off));
  if (lane == 0) wmax[wave] = mymax;
#pragma unroll
  for (int j = 0; j < 8; j++)
    if (t8[j] != -INFINITY) atomicAdd(&hist[fkey(t8[j]) >> 20], 1u);
  __syncthreads();
  if (tid == 0) {
    float m = -INFINITY;
    for (int w = 0; w < 16; w++) m = fmaxf(m, wmax[w]);
    m_sh = m;
  }
  if (wave == 1) {
    int base = lane * 64;
    uint32_t ssum = 0;
    for (int j = 0; j < 64; j++) ssum += hist[base + ((j + lane) & 63)];
    uint32_t incl = ssum;
    for (int off = 1; off < 64; off <<= 1) {
      uint32_t vv = __shfl_down(incl, off);
      if (lane + off < 64) incl += vv;
    }
    uint32_t higher = incl - ssum;
    if (higher < (uint32_t)k && incl >= (uint32_t)k) {
      uint32_t run = higher;
      for (int j = 63; j >= 0; j--) {
        run += hist[base + j];
        if (run >= (uint32_t)k) { beta_sh = base + j; break; }
      }
    }
  }
  __syncthreads();
  const float m = m_sh;
  const uint32_t keyT = (uint32_t)((beta_sh >= 1 ? beta_sh - 1 : 0)) << 20;
  double dsum = 0.0;
  for (int v = tid; v < V; v += NT1) {
    float s = row[v] / T;
    float e = expf(s - m);
    dsum += (double)e;
    if (fkey(s) >= keyT) {
      int pos = atomicAdd(&cnum_sh, 1);
      if (pos < CAP1) { cand_p[pos] = e; cand_i[pos] = v; }
    }
  }
  for (int off = 32; off > 0; off >>= 1)
    dsum += __shfl_down(dsum, off);
  if (lane == 0) wsum[wave] = dsum;
  __syncthreads();
  if (tid == 0) {
    double t = 0.0;
    for (int w = 0; w < 16; w++) t += wsum[w];
    D_sh = (float)t;
  }
  __syncthreads();
  const float D = D_sh;
  const int C = (cnum_sh < CAP1) ? cnum_sh : CAP1;
  for (int i = tid; i < C; i += NT1) cand_p[i] = cand_p[i] / D;
  __syncthreads();
  for (int i = tid; i < C; i += NT1) {
    float pi = cand_p[i];
    int   ii = cand_i[i];
    int r = 0;
    for (int j = 0; j < C; j++) {
      float pj = cand_p[j];
      r += (pj > pi) || (pj == pi && cand_i[j] < ii);
    }
    if (r < k) { svals[r] = pi; sidx[r] = ii; }
  }
  __syncthreads();
  if (tid == 0) {
    float cum = 0.f;
    int L = 1;
    for (int j = 0; j < k; j++) {
      cum += svals[j];
      if (j == 0) continue;
      if (cum <= 0.9f) L = j + 1; else break;
    }
    L_sh = L;
  }
  __syncthreads();
  const int L = L_sh;
  if (tid < L) {
    uint32_t kn0, kn1;
    threefry2x32(0u, 0u, 0u, 1u, kn0, kn1);
    unsigned long long total = (unsigned long long)B * (unsigned long long)V;
    unsigned long long flat = (unsigned long long)b * (unsigned long long)V
                            + (unsigned long long)sidx[tid];
    cand_p[tid] = svals[tid] / jax_noise(kn0, kn1, flat, total);
  }
  __syncthreads();
  if (tid == 0) {
    float bs = -1.0f;
    int   bi = INT_MAX;
    for (int j = 0; j < L; j++) {
      if (cand_p[j] > bs || (cand_p[j] == bs && sidx[j] < bi)) { bs = cand_p[j]; bi = sidx[j]; }
    }
    out[b] = bi;
  }
}

extern "C" void kernel_launch(void* const* d_in, const int* in_sizes, int n_in,
                              void* d_out, int out_size, void* d_ws, size_t ws_size,
                              hipStream_t stream) {
  const float* logits = (const float*)d_in[0];
  const float* temps  = (const float*)d_in[1];
  const int*   topk   = (const int*)d_in[2];
  int* out = (int*)d_out;

  int B = in_sizes[1];
  int V = in_sizes[0] / B;

  // ~32k elements per split block: B*S blocks ~= 2 per CU at B=128, V=128k.
  int S = (V + CHUNK_TARGET - 1) / CHUNK_TARGET;
  if (S > SMAX) S = SMAX;
  if (S < 1) S = 1;
  size_t need;
  for (;;) {
    need = (size_t)B * S * (sizeof(double) + sizeof(float) + sizeof(int))
         + (size_t)B * S * CAPS * sizeof(float2);
    if (need <= ws_size || S <= 2) break;
    S >>= 1;
  }

  if (ws_size < need || S < 2) {
    sampler_fallback<<<dim3(B), dim3(NT1), 0, stream>>>(logits, temps, topk, out, B, V);
    return;
  }

  int chunk = (((V + S - 1) / S) + 3) & ~3;   // multiple of 4 for float4 paths

  double* dsumArr = (double*)d_ws;
  float*  msArr   = (float*)(dsumArr + (size_t)B * S);
  int*    cntArr  = (int*)(msArr + (size_t)B * S);
  float2* pairs   = (float2*)(cntArr + (size_t)B * S);

  sampler_stream<<<dim3(B * S), dim3(NTK), 0, stream>>>(
      logits, temps, topk, msArr, dsumArr, cntArr, pairs, B, V, S, chunk);
  sampler_finalize<<<dim3(B), dim3(NTK), 0, stream>>>(
      temps, topk, msArr, dsumArr, cntArr, pairs, out, B, V, S);
}

// Round 8
// 118.945 us; speedup vs baseline: 1.0730x; 1.0730x over previous
//
#include <hip/hip_runtime.h>
#include <stdint.h>
#include <limits.h>

// Flip to 0 if validation shows wrong RNG path (legacy non-partitionable threefry).
#define THREEFRY_PARTITIONABLE 1

#define NTK   512      // threads per block (both kernels): 8 waves
#define NWAVE (NTK/64)
#define NBUCK 4096     // histogram buckets (monotone float key >> 20)
#define BPT   (NBUCK/NTK)   // buckets per thread in the block scan (8)
#define CAPS  256      // per-split candidate cap (workspace)
#define CAPG  2048     // per-row gathered candidate cap (LDS, finalize)
#define CAPF  512      // per-row filtered candidate cap (LDS, finalize)
#define KMAX  512      // max supported top_k
#define SMAX  32
#define CHUNK_TARGET 16384   // ~elements per split block -> S=8 at V=128k

// ---- fallback (round-1 proven) kernel constants ----
#define NT1   1024
#define CAP1  4096

#if __has_builtin(__builtin_amdgcn_exp2f)
#define FAST_EXP2(x) __builtin_amdgcn_exp2f(x)
#else
#define FAST_EXP2(x) exp2f(x)
#endif

__device__ __forceinline__ uint32_t rotl32(uint32_t v, int r) {
  return (v << r) | (v >> (32 - r));
}
__device__ __forceinline__ void tfround(uint32_t& x0, uint32_t& x1, int r) {
  x0 += x1; x1 = rotl32(x1, r); x1 ^= x0;
}
// JAX threefry2x32: 20 rounds, rotations [13,15,26,6]/[17,29,16,24]
__device__ __forceinline__ void threefry2x32(uint32_t k0, uint32_t k1,
                                             uint32_t x0, uint32_t x1,
                                             uint32_t& o0, uint32_t& o1) {
  uint32_t k2 = k0 ^ k1 ^ 0x1BD11BDAu;
  x0 += k0; x1 += k1;
  tfround(x0,x1,13); tfround(x0,x1,15); tfround(x0,x1,26); tfround(x0,x1,6);
  x0 += k1; x1 += k2 + 1u;
  tfround(x0,x1,17); tfround(x0,x1,29); tfround(x0,x1,16); tfround(x0,x1,24);
  x0 += k2; x1 += k0 + 2u;
  tfround(x0,x1,13); tfround(x0,x1,15); tfround(x0,x1,26); tfround(x0,x1,6);
  x0 += k0; x1 += k1 + 3u;
  tfround(x0,x1,17); tfround(x0,x1,29); tfround(x0,x1,16); tfround(x0,x1,24);
  x0 += k1; x1 += k2 + 4u;
  tfround(x0,x1,13); tfround(x0,x1,15); tfround(x0,x1,26); tfround(x0,x1,6);
  x0 += k2; x1 += k0 + 5u;
  o0 = x0; o1 = x1;
}
// Exponential noise for flat element i: jax.random.exponential(fold_in(key(0),1))
__device__ __forceinline__ float jax_noise(uint32_t kn0, uint32_t kn1,
                                           unsigned long long i,
                                           unsigned long long total) {
  uint32_t o0, o1, bits;
#if THREEFRY_PARTITIONABLE
  threefry2x32(kn0, kn1, (uint32_t)(i >> 32), (uint32_t)(i & 0xFFFFFFFFull), o0, o1);
  bits = o0 ^ o1;
#else
  unsigned long long H = total >> 1;
  if (i < H) { threefry2x32(kn0, kn1, (uint32_t)i, (uint32_t)(i + H), o0, o1); bits = o0; }
  else       { threefry2x32(kn0, kn1, (uint32_t)(i - H), (uint32_t)i, o0, o1); bits = o1; }
#endif
  float u = __uint_as_float((bits >> 9) | 0x3f800000u) - 1.0f;  // [0,1)
  float e = -log1pf(-u);
  return fmaxf(e, 1e-10f);
}
// Monotone float -> uint32 key (total order preserving)
__device__ __forceinline__ uint32_t fkey(float f) {
  uint32_t u = __float_as_uint(f);
  return u ^ ((u >> 31) ? 0xFFFFFFFFu : 0x80000000u);
}
// Smallest float whose key >= keyT (bucket floor). keyT==0 -> -inf (emit all).
__device__ __forceinline__ float unfkey_floor(uint32_t keyT) {
  if (keyT == 0u) return -INFINITY;
  return __uint_as_float((keyT & 0x80000000u) ? (keyT ^ 0x80000000u) : ~keyT);
}
__device__ __forceinline__ int clamp_k(int k) {
  if (k < 1) k = 1;
  if (k > KMAX) k = KMAX;
  return k;
}

// Block-parallel suffix-scan of hist -> bucket of the rank-k largest entry.
// beta_sh must be pre-zeroed; hist filled and barrier'd before the call.
// Conservative when hist holds a subset (undercount -> lower bucket).
__device__ __forceinline__ void block_kth_bucket(uint32_t* hist, uint32_t* wtot,
                                                 int* beta_sh, int k,
                                                 int tid, int lane, int wave) {
  const int base = tid * BPT;
  uint32_t tsum = 0;
#pragma unroll
  for (int j = 0; j < BPT; j++) tsum += hist[base + j];
  uint32_t incl = tsum;                    // inclusive suffix over lanes >= lane
  for (int off = 1; off < 64; off <<= 1) {
    uint32_t v = __shfl_down(incl, off);
    if (lane + off < 64) incl += v;
  }
  if (lane == 0) wtot[wave] = incl;
  __syncthreads();
  uint32_t above = incl - tsum;            // threads strictly above (same wave)
  for (int w = wave + 1; w < NWAVE; w++) above += wtot[w];
  if (above < (uint32_t)k && above + tsum >= (uint32_t)k) {
    uint32_t run = above;
    for (int j = BPT - 1; j >= 0; j--) {
      run += hist[base + j];
      if (run >= (uint32_t)k) { *beta_sh = base + j; break; }
    }
  }
  __syncthreads();
}

// ========= K1: single streaming pass, 4-deep pipelined loads =========
// Per split: dsum_sp = sum_i 2^(l_i*log2e/T), f32 pairs -> f64 fold (no max
// subtraction: |l*log2e/T| << 127 for this data; K2 rescales by
// 2^(-m_g*log2e/T) in f64; D rel-err ~1e-6 << the 0.9-crossing margins).
// Selection on RAW logit bits (T>0, IEEE division monotone). Each thread
// tracks its top-2 (value,idx) branchlessly. Threshold: histogram of thread
// maxes -> conservative keyT (subset undercount => bucket <= true kth bucket).
// Emit: v0<fT -> nothing (all this thread's elems < fT); v1<fT<=v0 -> emit v0
// from registers; v1>=fT (rare) -> rescan this thread's slice. Emission set =
// ALL elements >= fT, identical to prior rounds => exactness preserved.
__global__ __launch_bounds__(NTK)
void sampler_stream(const float* __restrict__ logits,
                    const float* __restrict__ temps,
                    const int* __restrict__ topk_ptr,
                    float* __restrict__ msArr,
                    double* __restrict__ dsumArr,
                    int* __restrict__ cntArr,
                    float2* __restrict__ pairs,
                    int B, int V, int S, int chunk) {
  const int blk = blockIdx.x;
  const int b = blk / S, sp = blk % S;
  const int tid = threadIdx.x, lane = tid & 63, wave = tid >> 6;

  __shared__ uint32_t hist[NBUCK];
  __shared__ float wm[NWAVE];
  __shared__ double wsum[NWAVE];
  __shared__ uint32_t wtot[NWAVE];
  __shared__ int beta_sh, cnum_sh;

  if (tid == 0) { beta_sh = 0; cnum_sh = 0; }
  for (int i = tid; i < NBUCK; i += NTK) hist[i] = 0;

  const float T = temps[b];
  const float cf = (float)(1.4426950408889634 / (double)T);  // log2e / T
  const int k = clamp_k(*topk_ptr);

  const int start = sp * chunk;
  const int end = min(start + chunk, V);
  const float* row = logits + (size_t)b * (size_t)V;
  const int n = (end > start) ? (end - start) : 0;
  const int n4 = n >> 2;                 // start is 4-aligned (chunk % 4 == 0)
  const float4* row4 = (const float4*)(row + start);

  // per-thread state: branchless top-2 + exp2 accumulators
  float v0 = -INFINITY, v1 = -INFINITY;
  int   i0 = 0, i1 = 0;
  float acc0 = 0.f, acc1 = 0.f;

  auto proc = [&](float f, int idx) {
    bool gt0 = f > v0;
    bool gt1 = f > v1;
    float nv1 = gt0 ? v0 : (gt1 ? f : v1);
    int   ni1 = gt0 ? i0 : (gt1 ? idx : i1);
    v1 = nv1; i1 = ni1;
    v0 = gt0 ? f : v0;
    i0 = gt0 ? idx : i0;
  };
  auto proc4 = [&](float4 f, int vb) {
    proc(f.x, vb); proc(f.y, vb + 1); proc(f.z, vb + 2); proc(f.w, vb + 3);
    acc0 += FAST_EXP2(f.x * cf) + FAST_EXP2(f.z * cf);
    acc1 += FAST_EXP2(f.y * cf) + FAST_EXP2(f.w * cf);
  };

  // ---- streaming pass: 4 independent loads in flight per wave ----
  int i = tid;
  for (; i + 3 * NTK < n4; i += 4 * NTK) {
    float4 fa = row4[i];
    float4 fb = row4[i + NTK];
    float4 fc = row4[i + 2 * NTK];
    float4 fd = row4[i + 3 * NTK];
    proc4(fa, start + i * 4);
    proc4(fb, start + (i + NTK) * 4);
    proc4(fc, start + (i + 2 * NTK) * 4);
    proc4(fd, start + (i + 3 * NTK) * 4);
  }
  for (; i < n4; i += NTK) {
    float4 fa = row4[i];
    proc4(fa, start + i * 4);
  }
  for (int v = start + n4 * 4 + tid; v < end; v += NTK) {
    float f = row[v];
    proc(f, v);
    acc0 += FAST_EXP2(f * cf);
  }

  // wave reductions
  float bm = v0;
  for (int off = 32; off; off >>= 1)
    bm = fmaxf(bm, __shfl_down(bm, off));
  if (lane == 0) wm[wave] = bm;

  double ds = (double)acc0 + (double)acc1;
  for (int off = 32; off; off >>= 1)
    ds += __shfl_down(ds, off);
  if (lane == 0) wsum[wave] = ds;

  if (v0 != -INFINITY) atomicAdd(&hist[fkey(v0) >> 20], 1u);
  __syncthreads();                        // hist zero + wm + wsum + hist atomics

  if (tid == 0) {
    float m_sp = wm[0];
#pragma unroll
    for (int w = 1; w < NWAVE; w++) m_sp = fmaxf(m_sp, wm[w]);
    msArr[blk] = m_sp;
    double t = 0.0;
    for (int w = 0; w < NWAVE; w++) t += wsum[w];
    dsumArr[blk] = t;                     // RAW (unscaled) exp2 sum
  }

  block_kth_bucket(hist, wtot, &beta_sh, k, tid, lane, wave);

  const float fT = unfkey_floor((uint32_t)beta_sh << 20);
  float2* myp = pairs + (size_t)blk * CAPS;

  // ---- emit: registers for the common case, rescan only on >=2 hits ----
  if (v0 >= fT) {
    if (v1 >= fT) {
      // rare: this thread holds >=2 elements above threshold -> exact rescan
      for (int i2 = tid; i2 < n4; i2 += NTK) {
        float4 f = row4[i2];              // L2-warm, few threads active
        const int vb = start + i2 * 4;
        if (f.x >= fT) { int p = atomicAdd(&cnum_sh, 1); if (p < CAPS) myp[p] = make_float2(f.x, __int_as_float(vb)); }
        if (f.y >= fT) { int p = atomicAdd(&cnum_sh, 1); if (p < CAPS) myp[p] = make_float2(f.y, __int_as_float(vb + 1)); }
        if (f.z >= fT) { int p = atomicAdd(&cnum_sh, 1); if (p < CAPS) myp[p] = make_float2(f.z, __int_as_float(vb + 2)); }
        if (f.w >= fT) { int p = atomicAdd(&cnum_sh, 1); if (p < CAPS) myp[p] = make_float2(f.w, __int_as_float(vb + 3)); }
      }
      for (int v = start + n4 * 4 + tid; v < end; v += NTK) {
        float f = row[v];
        if (f >= fT) { int p = atomicAdd(&cnum_sh, 1); if (p < CAPS) myp[p] = make_float2(f, __int_as_float(v)); }
      }
    } else {
      int p = atomicAdd(&cnum_sh, 1);
      if (p < CAPS) myp[p] = make_float2(v0, __int_as_float(i0));
    }
  }
  __syncthreads();
  if (tid == 0) cntArr[blk] = min(cnum_sh, CAPS);
}

// ==================== K2: per-row finalize ====================
__global__ __launch_bounds__(NTK)
void sampler_finalize(const float* __restrict__ temps,
                      const int* __restrict__ topk_ptr,
                      const float* __restrict__ msArr,
                      const double* __restrict__ dsumArr,
                      const int* __restrict__ cntArr,
                      const float2* __restrict__ pairs,
                      int* __restrict__ out,
                      int B, int V, int S) {
  const int b = blockIdx.x;
  const int tid = threadIdx.x, lane = tid & 63, wave = tid >> 6;

  __shared__ uint32_t hist[NBUCK];
  __shared__ float gv[CAPG];
  __shared__ int   gi[CAPG];
  __shared__ float c2v[CAPF];
  __shared__ int   c2i[CAPF];
  __shared__ float c2p[CAPF];
  __shared__ float sv[KMAX];
  __shared__ int   si[KMAX];
  __shared__ float sc[KMAX];
  __shared__ int   offL[SMAX + 1];
  __shared__ int   cnL[SMAX];
  __shared__ float msL[SMAX];
  __shared__ double dsL[SMAX];
  __shared__ uint32_t wtot[NWAVE];
  __shared__ int beta_sh, cnt2_sh, L_sh;
  __shared__ float m_sh, D_sh;

  const int k = clamp_k(*topk_ptr);
  const float T = temps[b];

  if (tid == 0) { beta_sh = 0; cnt2_sh = 0; }
  if (tid < S) {                          // parallel preload of ALL split scalars
    msL[tid] = msArr[b * S + tid];
    dsL[tid] = dsumArr[b * S + tid];
    int c = cntArr[b * S + tid];
    cnL[tid] = (c < CAPS) ? c : CAPS;
  }
  for (int i = tid; i < NBUCK; i += NTK) hist[i] = 0;
  __syncthreads();

  if (tid == 0) {                         // prefix offsets from LDS (fast)
    int acc = 0;
    for (int j = 0; j < S; j++) { offL[j] = acc; acc += cnL[j]; }
    offL[S] = acc;
  }

  // D = float( (sum_sp raw_sp) * 2^(-m_g*log2e/T) ), f64 rescale once per row
  if (wave == 1 || (NWAVE == 1 && wave == 0)) {
    float msp = (lane < S) ? msL[lane] : -INFINITY;
    float mg = msp;
    for (int off = 32; off; off >>= 1)
      mg = fmaxf(mg, __shfl_down(mg, off));
    mg = __shfl(mg, 0);
    double term = (lane < S) ? dsL[lane] : 0.0;
    for (int off = 32; off; off >>= 1)
      term += __shfl_down(term, off);
    if (lane == 0) {
      const double cd = 1.4426950408889634 / (double)T;
      D_sh = (float)(term * exp2(-(double)mg * cd));
      m_sh = mg / T;     // == max over fl(l/T) (monotone IEEE division)
    }
  }
  __syncthreads();

  const int TC = min(offL[S], CAPG);

  // flat parallel gather of all candidates into LDS + exact-count histogram
  for (int t = tid; t < TC; t += NTK) {
    int j = 0;
#pragma unroll
    for (int jj = 1; jj <= SMAX; jj++)
      if (jj <= S) j += (t >= offL[jj]);
    float2 pr = pairs[(size_t)(b * S + j) * CAPS + (t - offL[j])];
    gv[t] = pr.x;
    gi[t] = __float_as_int(pr.y);
    atomicAdd(&hist[fkey(pr.x) >> 20], 1u);
  }
  __syncthreads();

  block_kth_bucket(hist, wtot, &beta_sh, k, tid, lane, wave);

  // filter down to elements >= global kth bucket floor (exact counts ->
  // bucket <= true kth element's bucket -> keep set superset of row top-k)
  const float fT = unfkey_floor((uint32_t)beta_sh << 20);
  for (int t = tid; t < TC; t += NTK) {
    float val = gv[t];
    if (val >= fT) {
      int pos = atomicAdd(&cnt2_sh, 1);
      if (pos < CAPF) { c2v[pos] = val; c2i[pos] = gi[t]; }
    }
  }
  __syncthreads();

  const int C = min(cnt2_sh, CAPF);
  const float m = m_sh, D = D_sh;
  // exact-path p for the ~150 survivors: real IEEE div + libm expf
  for (int i = tid; i < C; i += NTK)
    c2p[i] = expf(c2v[i] / T - m) / D;
  __syncthreads();

  // exact ranking: (p desc, idx asc) — JAX top_k / stable argsort tie rule
  for (int i = tid; i < C; i += NTK) {
    float pi = c2p[i];
    int   ii = c2i[i];
    int r = 0;
    for (int j = 0; j < C; j++) {
      float pj = c2p[j];
      r += (pj > pi) || (pj == pi && c2i[j] < ii);
    }
    if (r < k) { sv[r] = pi; si[r] = ii; }
  }
  __syncthreads();

  // top-p: sequential fp32 cumsum, keep prefix (first always kept)
  const int kk = (k < C) ? k : C;
  if (tid == 0) {
    float cum = 0.f;
    int L = 1;
    for (int j = 0; j < kk; j++) {
      cum += sv[j];
      if (j == 0) continue;
      if (cum <= 0.9f) L = j + 1; else break;
    }
    L_sh = L;
  }
  __syncthreads();

  const int L = L_sh;
  {
    uint32_t kn0, kn1;
    threefry2x32(0u, 0u, 0u, 1u, kn0, kn1);   // fold_in(key(0), 1)
    unsigned long long total = (unsigned long long)B * (unsigned long long)V;
    for (int j = tid; j < L; j += NTK) {
      unsigned long long flat = (unsigned long long)b * (unsigned long long)V
                              + (unsigned long long)si[j];
      sc[j] = sv[j] / jax_noise(kn0, kn1, flat, total);
    }
  }
  __syncthreads();

  if (tid == 0) {
    float bs = -1.0f;
    int   bi = INT_MAX;
    for (int j = 0; j < L; j++) {
      if (sc[j] > bs || (sc[j] == bs && si[j] < bi)) { bs = sc[j]; bi = si[j]; }
    }
    out[b] = bi;
  }
}

// ==================== Fallback: round-1 proven single kernel ==================
__global__ __launch_bounds__(NT1, 1)
void sampler_fallback(const float* __restrict__ logits,
                      const float* __restrict__ temps,
                      const int* __restrict__ topk_ptr,
                      int* __restrict__ out,
                      int B, int V) {
  const int b    = blockIdx.x;
  const int tid  = threadIdx.x;
  const int lane = tid & 63;
  const int wave = tid >> 6;

  __shared__ uint32_t hist[NBUCK];
  __shared__ float    cand_p[CAP1];
  __shared__ int      cand_i[CAP1];
  __shared__ float    wmax[16];
  __shared__ double   wsum[16];
  __shared__ float    svals[KMAX];
  __shared__ int      sidx[KMAX];
  __shared__ float    m_sh, D_sh;
  __shared__ int      beta_sh, cnum_sh, L_sh;

  const float T = temps[b];
  const float* row = logits + (size_t)b * (size_t)V;
  int k = clamp_k(*topk_ptr);
  if (k > V) k = V;

  if (tid == 0) { beta_sh = 1; cnum_sh = 0; }
  for (int i = tid; i < NBUCK; i += NT1) hist[i] = 0;
  __syncthreads();

  float t8[8];
#pragma unroll
  for (int j = 0; j < 8; j++) t8[j] = -INFINITY;
  float mymax = -INFINITY;
  for (int v = tid; v < V; v += NT1) {
    float s = row[v] / T;
    mymax = fmaxf(mymax, s);
    if (s > t8[0]) {
      t8[0] = s;
#pragma unroll
      for (int j = 1; j < 8; j++)
        if (t8[j-1] > t8[j]) { float tmp = t8[j]; t8[j] = t8[j-1]; t8[j-1] = tmp; }
    }
  }
  for (int off = 32; off > 0; off >>= 1)
    mymax = fmaxf(mymax, __shfl_down(mymax, off));
  if (lane == 0) wmax[wave] = mymax;
#pragma unroll
  for (int j = 0; j < 8; j++)
    if (t8[j] != -INFINITY) atomicAdd(&hist[fkey(t8[j]) >> 20], 1u);
  __syncthreads();
  if (tid == 0) {
    float m = -INFINITY;
    for (int w = 0; w < 16; w++) m = fmaxf(m, wmax[w]);
    m_sh = m;
  }
  if (wave == 1) {
    int base = lane * 64;
    uint32_t ssum = 0;
    for (int j = 0; j < 64; j++) ssum += hist[base + ((j + lane) & 63)];
    uint32_t incl = ssum;
    for (int off = 1; off < 64; off <<= 1) {
      uint32_t vv = __shfl_down(incl, off);
      if (lane + off < 64) incl += vv;
    }
    uint32_t higher = incl - ssum;
    if (higher < (uint32_t)k && incl >= (uint32_t)k) {
      uint32_t run = higher;
      for (int j = 63; j >= 0; j--) {
        run += hist[base + j];
        if (run >= (uint32_t)k) { beta_sh = base + j; break; }
      }
    }
  }
  __syncthreads();
  const float m = m_sh;
  const uint32_t keyT = (uint32_t)((beta_sh >= 1 ? beta_sh - 1 : 0)) << 20;
  double dsum = 0.0;
  for (int v = tid; v < V; v += NT1) {
    float s = row[v] / T;
    float e = expf(s - m);
    dsum += (double)e;
    if (fkey(s) >= keyT) {
      int pos = atomicAdd(&cnum_sh, 1);
      if (pos < CAP1) { cand_p[pos] = e; cand_i[pos] = v; }
    }
  }
  for (int off = 32; off > 0; off >>= 1)
    dsum += __shfl_down(dsum, off);
  if (lane == 0) wsum[wave] = dsum;
  __syncthreads();
  if (tid == 0) {
    double t = 0.0;
    for (int w = 0; w < 16; w++) t += wsum[w];
    D_sh = (float)t;
  }
  __syncthreads();
  const float D = D_sh;
  const int C = (cnum_sh < CAP1) ? cnum_sh : CAP1;
  for (int i = tid; i < C; i += NT1) cand_p[i] = cand_p[i] / D;
  __syncthreads();
  for (int i = tid; i < C; i += NT1) {
    float pi = cand_p[i];
    int   ii = cand_i[i];
    int r = 0;
    for (int j = 0; j < C; j++) {
      float pj = cand_p[j];
      r += (pj > pi) || (pj == pi && cand_i[j] < ii);
    }
    if (r < k) { svals[r] = pi; sidx[r] = ii; }
  }
  __syncthreads();
  if (tid == 0) {
    float cum = 0.f;
    int L = 1;
    for (int j = 0; j < k; j++) {
      cum += svals[j];
      if (j == 0) continue;
      if (cum <= 0.9f) L = j + 1; else break;
    }
    L_sh = L;
  }
  __syncthreads();
  const int L = L_sh;
  if (tid < L) {
    uint32_t kn0, kn1;
    threefry2x32(0u, 0u, 0u, 1u, kn0, kn1);
    unsigned long long total = (unsigned long long)B * (unsigned long long)V;
    unsigned long long flat = (unsigned long long)b * (unsigned long long)V
                            + (unsigned long long)sidx[tid];
    cand_p[tid] = svals[tid] / jax_noise(kn0, kn1, flat, total);
  }
  __syncthreads();
  if (tid == 0) {
    float bs = -1.0f;
    int   bi = INT_MAX;
    for (int j = 0; j < L; j++) {
      if (cand_p[j] > bs || (cand_p[j] == bs && sidx[j] < bi)) { bs = cand_p[j]; bi = sidx[j]; }
    }
    out[b] = bi;
  }
}

extern "C" void kernel_launch(void* const* d_in, const int* in_sizes, int n_in,
                              void* d_out, int out_size, void* d_ws, size_t ws_size,
                              hipStream_t stream) {
  const float* logits = (const float*)d_in[0];
  const float* temps  = (const float*)d_in[1];
  const int*   topk   = (const int*)d_in[2];
  int* out = (int*)d_out;

  int B = in_sizes[1];
  int V = in_sizes[0] / B;

  // ~16k elements per split block: B*S = 1024 blocks -> 4/CU -> full 32 waves.
  int S = (V + CHUNK_TARGET - 1) / CHUNK_TARGET;
  if (S > SMAX) S = SMAX;
  if (S < 1) S = 1;
  size_t need;
  for (;;) {
    need = (size_t)B * S * (sizeof(double) + sizeof(float) + sizeof(int))
         + (size_t)B * S * CAPS * sizeof(float2);
    if (need <= ws_size || S <= 2) break;
    S >>= 1;
  }

  if (ws_size < need || S < 2) {
    sampler_fallback<<<dim3(B), dim3(NT1), 0, stream>>>(logits, temps, topk, out, B, V);
    return;
  }

  int chunk = (((V + S - 1) / S) + 3) & ~3;   // multiple of 4 for float4 paths

  double* dsumArr = (double*)d_ws;
  float*  msArr   = (float*)(dsumArr + (size_t)B * S);
  int*    cntArr  = (int*)(msArr + (size_t)B * S);
  float2* pairs   = (float2*)(cntArr + (size_t)B * S);

  sampler_stream<<<dim3(B * S), dim3(NTK), 0, stream>>>(
      logits, temps, topk, msArr, dsumArr, cntArr, pairs, B, V, S, chunk);
  sampler_finalize<<<dim3(B), dim3(NTK), 0, stream>>>(
      temps, topk, msArr, dsumArr, cntArr, pairs, out, B, V, S);
}